// Round 17
// baseline (501.466 us; speedup 1.0000x reference)
//
#include <hip/hip_runtime.h>
#include <cstdint>
#include <cstddef>

#define BATCH 8
#define CIN 64
#define HIN 70
#define HOUT 64
#define NPIX 4096
#define MPIX 1024

typedef __attribute__((ext_vector_type(8))) short short8;
typedef __attribute__((ext_vector_type(4))) float f32x4;
typedef __attribute__((ext_vector_type(4))) unsigned int uint4v;

__device__ __forceinline__ unsigned short f2bf_rne(float f) {
  unsigned int u = __builtin_bit_cast(unsigned int, f);
  unsigned int r = (u + 0x7FFFu + ((u >> 16) & 1u)) >> 16;
  return (unsigned short)r;
}

__device__ __forceinline__ unsigned int rot16(unsigned int u) {
  return (u >> 16) | (u << 16);
}

__device__ __forceinline__ short8 rot16x4(short8 v) {
  uint4v u = __builtin_bit_cast(uint4v, v);
  u.x = rot16(u.x); u.y = rot16(u.y); u.z = rot16(u.z); u.w = rot16(u.w);
  return __builtin_bit_cast(short8, u);
}

// ---------------------------------------------------------------------------
// prep_x: x -> xTi [8][70][70][128us] dual (hi,lo) pairs
//            + xTi_h [8][70][70][64us] hi-only (for single-bf16 g path)
// ---------------------------------------------------------------------------
__global__ __launch_bounds__(256) void prep_x(const float* __restrict__ x,
                                              unsigned int* __restrict__ xTi,
                                              unsigned int* __restrict__ xTi_h) {
  __shared__ float tile[64][71];
  const int blk = blockIdx.x;  // 0..559
  const int b = blk / 70;
  const int r = blk - b * 70;
  const int t = threadIdx.x;
  for (int i = t; i < 64 * 70; i += 256) {
    int ci = i / 70;
    int c = i - ci * 70;
    tile[ci][c] = x[(((size_t)(b * 64 + ci)) * 70 + r) * 70 + c];
  }
  __syncthreads();
  for (int i = t; i < 70 * 64; i += 256) {
    int c = i >> 6;
    int ci = i & 63;
    float a = tile[ci][c];
    unsigned short hi = f2bf_rne(a);
    float hif = __builtin_bit_cast(float, ((unsigned int)hi) << 16);
    unsigned short lo = f2bf_rne(a - hif);
    xTi[(((size_t)(b * 70 + r)) * 70 + c) * 64 + ci] =
        (unsigned int)hi | (((unsigned int)lo) << 16);
  }
  for (int i = t; i < 70 * 32; i += 256) {
    int c = i >> 5;
    int dwi = i & 31;
    unsigned int h0 = f2bf_rne(tile[2 * dwi][c]);
    unsigned int h1 = f2bf_rne(tile[2 * dwi + 1][c]);
    xTi_h[(((size_t)(b * 70 + r)) * 70 + c) * 32 + dwi] = h0 | (h1 << 16);
  }
}

// ---------------------------------------------------------------------------
// prep_w: wTi [49][448][64dw] dual pairs + biasPad[448]
//         wTi_s [49][192][32dw] hi-only (OC 256..447 = g[56..199] + pad)
// ---------------------------------------------------------------------------
__global__ __launch_bounds__(256) void prep_w(
    const float* __restrict__ tw, const float* __restrict__ pw,
    const float* __restrict__ gw,
    const float* __restrict__ tb, const float* __restrict__ pb,
    const float* __restrict__ gb,
    unsigned int* __restrict__ wTi, unsigned int* __restrict__ wTi_s,
    float* __restrict__ biasPad) {
  int gid = blockIdx.x * 256 + threadIdx.x;
  if (gid < 1404928) {  // 49*448*64 dual dwords
    if (gid < 448) {
      float bv = 0.0f;
      if (gid < 100) bv = tb[gid];
      else if (gid < 200) bv = pb[gid - 100];
      else if (gid < 400) bv = gb[gid - 200];
      biasPad[gid] = bv;
    }
    int ci = gid & 63;
    int OC = (gid >> 6) % 448;
    int s = gid / (448 * 64);
    float v = 0.0f;
    if (OC < 100) v = tw[((size_t)(OC * 64 + ci)) * 49 + s];
    else if (OC < 200) v = pw[((size_t)((OC - 100) * 64 + ci)) * 49 + s];
    else if (OC < 400) v = gw[((size_t)((OC - 200) * 64 + ci)) * 49 + s];
    unsigned short hi = f2bf_rne(v);
    float hif = __builtin_bit_cast(float, ((unsigned int)hi) << 16);
    unsigned short lo = f2bf_rne(v - hif);
    wTi[gid] = (unsigned int)hi | (((unsigned int)lo) << 16);
  } else if (gid < 1404928 + 301056) {  // 49*192*32 single dwords
    int g2 = gid - 1404928;
    int dwi = g2 & 31;
    int OCl = (g2 >> 5) % 192;
    int s = g2 / (192 * 32);
    int gc = 56 + OCl;
    float v0 = 0.0f, v1 = 0.0f;
    if (gc < 200) {
      v0 = gw[((size_t)(gc * 64 + 2 * dwi)) * 49 + s];
      v1 = gw[((size_t)(gc * 64 + 2 * dwi + 1)) * 49 + s];
    }
    wTi_s[g2] = (unsigned int)f2bf_rne(v0) |
                (((unsigned int)f2bf_rne(v1)) << 16);
  }
}

// ---------------------------------------------------------------------------
// convmfma v6 (unchanged from r13/r15/r16, verified): 256-thr / 4-wave,
// wave = 2 rows; DUAL (theta/phi/g 0..55) + single-bf16 (g 56..199).
// ---------------------------------------------------------------------------
template <bool DUAL>
__global__ __launch_bounds__(256, 2) void convmfma_kernel(
    const unsigned short* __restrict__ xT,
    const unsigned short* __restrict__ wT,
    const float* __restrict__ biasPad,
    unsigned int* __restrict__ thd_dw,
    unsigned int* __restrict__ phd_dw,
    unsigned short* __restrict__ gP) {
  __shared__ __align__(16) char smem[62720 + 16384];
  const int LDSW = 62720;
  const int NCH = DUAL ? 4 : 2;
  const int XS = DUAL ? 128 : 64;
  const int WOCS = DUAL ? 128 : 64;
  const int WSTRIDE = DUAL ? 57344 : 12288;

  const int gx = blockIdx.x;
  const int b = gx >> 3;
  const int ptile = gx & 7;
  const int oy0 = ptile * 8;
  const int oc0 = (DUAL ? 0 : 256) + (blockIdx.y << 6);
  const int oc0W = DUAL ? oc0 : (blockIdx.y << 6);

  const int t = threadIdx.x;
  const int wv = t >> 6;
  const int l = t & 63;
  const int lm = l & 15;
  const int lg = l >> 4;

  int wdstOff_[2];
  const unsigned short* wsrc_[2];
  const int keyA = ((lm >> 1) & 3) << 4;
  const int laneA = (lm << 6) + ((lg << 4) ^ keyA);

  f32x4 acc[4][2][4];
#pragma unroll
  for (int j = 0; j < 4; ++j)
#pragma unroll
    for (int rr = 0; rr < 2; ++rr)
#pragma unroll
      for (int f = 0; f < 4; ++f) acc[j][rr][f] = (f32x4)0.0f;

  for (int chunk = 0; chunk < NCH; ++chunk) {
    for (int i = t; i < 3920; i += 256) {
      int idx70 = i >> 2;
      int s16 = i & 3;
      int rr = idx70 / 70;
      int cc = idx70 - rr * 70;
      const unsigned short* src =
          xT + ((size_t)((b * 70 + oy0 + rr) * 70 + cc)) * XS +
          (chunk << 5) + (s16 << 3);
      short8 v = *(const short8*)src;
      int dst = (idx70 << 6) + ((s16 << 4) ^ (((cc >> 1) & 3) << 4));
      *(short8*)(smem + dst) = v;
    }
    short8 wreg[2];
#pragma unroll
    for (int u2 = 0; u2 < 2; ++u2) {
      int u = t + (u2 << 8);
      int sub = u >> 8;
      int oc_t = (u >> 2) & 63;
      int q = u & 3;
      wdstOff_[u2] =
          sub * 4096 + (oc_t << 6) + ((q << 4) ^ (((oc_t >> 1) & 3) << 4));
      wsrc_[u2] = wT + (size_t)(oc0W + oc_t) * WOCS + (chunk << 5) + (q << 3);
      wreg[u2] = *(const short8*)(wsrc_[u2] + (size_t)sub * WSTRIDE);
      *(short8*)(smem + LDSW + wdstOff_[u2]) = wreg[u2];
      wreg[u2] = *(const short8*)(wsrc_[u2] + (size_t)(2 + sub) * WSTRIDE);
    }
    __syncthreads();

    for (int p = 0; p < 25; ++p) {
      const char* slotBase = smem + LDSW + ((p & 1) << 13);
#pragma unroll
      for (int halfs = 0; halfs < 2; ++halfs) {
        const int s = 2 * p + halfs;
        if (s <= 48) {
          const int ky = s / 7;
          const int kx = s - ky * 7;
          const char* wb = slotBase + (halfs << 12) + laneA;
          short8 aW[4], aS[4];
#pragma unroll
          for (int j = 0; j < 4; ++j) {
            aW[j] = *(const short8*)(wb + j * 1024);
            if (DUAL) aS[j] = rot16x4(aW[j]);
          }
          const int klx = kx + lm;
          const int key = ((klx >> 1) & 3) << 4;
#pragma unroll
          for (int rr = 0; rr < 2; ++rr) {
            const char* bbase =
                smem + ((2 * wv + rr + ky) * 70 + klx) * 64 + ((lg << 4) ^ key);
#pragma unroll
            for (int f = 0; f < 4; ++f) {
              short8 bf = *(const short8*)(bbase + f * 1024);
#pragma unroll
              for (int j = 0; j < 4; ++j) {
                acc[j][rr][f] = __builtin_amdgcn_mfma_f32_16x16x32_bf16(
                    aW[j], bf, acc[j][rr][f], 0, 0, 0);
                if (DUAL)
                  acc[j][rr][f] = __builtin_amdgcn_mfma_f32_16x16x32_bf16(
                      aS[j], bf, acc[j][rr][f], 0, 0, 0);
              }
            }
          }
        }
      }
      if (p < 24) {
#pragma unroll
        for (int u2 = 0; u2 < 2; ++u2) {
          *(short8*)(smem + LDSW + (((p + 1) & 1) << 13) + wdstOff_[u2]) =
              wreg[u2];
          if (p < 23) {
            int sub = (t + (u2 << 8)) >> 8;
            int snext = 2 * (p + 2) + sub;
            if (snext > 48) snext = 48;
            wreg[u2] = *(const short8*)(wsrc_[u2] + (size_t)snext * WSTRIDE);
          }
        }
      }
      __syncthreads();
    }
  }

  float bia[4][4];
#pragma unroll
  for (int j = 0; j < 4; ++j)
#pragma unroll
    for (int r = 0; r < 4; ++r) bia[j][r] = biasPad[oc0 + j * 16 + lg * 4 + r];

  if (DUAL) {
#pragma unroll
    for (int j = 0; j < 4; ++j) {
#pragma unroll
      for (int rr = 0; rr < 2; ++rr) {
#pragma unroll
        for (int f = 0; f < 4; ++f) {
#pragma unroll
          for (int r = 0; r < 4; ++r) {
            int ch = oc0 + j * 16 + lg * 4 + r;
            if (ch < 128) {
              int n = (oy0 + 2 * wv + rr) * 64 + f * 16 + lm;
              unsigned int outw = 0u;
              if (ch < 100) {
                float v = acc[j][rr][f][r] + bia[j][r];
                unsigned short hi = f2bf_rne(v);
                float hif =
                    __builtin_bit_cast(float, ((unsigned int)hi) << 16);
                unsigned short lo = f2bf_rne(v - hif);
                outw = (unsigned int)hi | (((unsigned int)lo) << 16);
              }
              thd_dw[(((size_t)(b << 12) + n) << 7) + ch] = outw;
            }
          }
        }
      }
    }
  }

#pragma unroll
  for (int j = 0; j < 4; ++j) {
#pragma unroll
    for (int f = 0; f < 4; ++f) {
#pragma unroll
      for (int r = 0; r < 4; ++r) {
        float v0 = acc[j][0][f][r] + bia[j][r];
        float v1 = acc[j][1][f][r] + bia[j][r];
        float vr = fmaxf(v0, v1);
        float vn = fmaxf(vr, __shfl_xor(vr, 1));
        if (!(lm & 1)) {
          int ch = oc0 + j * 16 + lg * 4 + r;
          int m = (((oy0 >> 1) + wv) << 5) + f * 8 + (lm >> 1);
          if (DUAL) {
            if (ch >= 100 && ch < 200) {
              int c = ch - 100;
              unsigned short hi = f2bf_rne(vn);
              float hif = __builtin_bit_cast(float, ((unsigned int)hi) << 16);
              unsigned short lo = f2bf_rne(vn - hif);
              phd_dw[(((size_t)(b << 10) + m) << 7) + c] =
                  (unsigned int)hi | (((unsigned int)lo) << 16);
            } else if (ch >= 200) {
              gP[((size_t)(b * 208 + (ch - 200)) << 10) + m] = f2bf_rne(vn);
              if (ch < 228)
                phd_dw[(((size_t)(b << 10) + m) << 7) + (ch - 100)] = 0u;
            }
          } else {
            int cg = ch - 200;
            if (cg < 208)
              gP[((size_t)(b * 208 + cg) << 10) + m] = f2bf_rne(vn);
          }
        }
      }
    }
  }
}

// ---------------------------------------------------------------------------
// attn v7: flash-fused (r16 structure) UNDER the 128-VGPR cliff.
// Change vs r16: theta frags re-loaded from global each step (L1-hot 8KB
// row) instead of cached in aA[8] (-32 VGPR); __launch_bounds__(256,4)
// pins the allocator at 128 VGPR -> 4 waves/SIMD (m69: cliff at 128).
// ---------------------------------------------------------------------------
__global__ __launch_bounds__(256, 4) void attn_kernel(
    const unsigned short* __restrict__ thd,  // [8][4096][256]
    const unsigned short* __restrict__ phd,  // [8][1024][256]
    const unsigned short* __restrict__ gP,   // [8][208][1024]
    float* __restrict__ out) {               // [8][200][4096]
  __shared__ __align__(16) float outAcc[16][212];
  __shared__ float statsL[4][16][2];
  __shared__ float mFinL[16];
  __shared__ float invL[16];

  const int bx = blockIdx.x;   // 0..2047
  const int b = bx >> 8;
  const int n0 = (bx & 255) << 4;
  const int t = threadIdx.x;
  const int w = t >> 6;        // m-quarter 0..3
  const int l = t & 63;
  const int lm = l & 15;
  const int lg = l >> 4;

  // theta row base (8KB per block, L1-hot after step 0; re-read per step)
  const unsigned short* apBase =
      thd + (((size_t)(b << 12) + n0 + lm) << 8) + lg * 8;

  float mRun = -3.0e38f, sRun = 0.0f;
  f32x4 oacc[13];
#pragma unroll
  for (int i = 0; i < 13; ++i) oacc[i] = (f32x4)0.f;

  const int src1 = ((lg & 1) << 5) + lm;
  const int src2 = src1 + 16;
  const bool hi2 = (lg >> 1) != 0;
  const int rbase = lg << 2;

#pragma unroll
  for (int step = 0; step < 8; ++step) {
    const int m0 = (w << 8) + (step << 5);
    // ---- QK^T (theta frags re-loaded; swap recomputed)
    f32x4 ac0 = (f32x4)0.f, ac1 = (f32x4)0.f;
    const unsigned short* bp0 =
        phd + (((size_t)(b << 10) + m0 + lm) << 8) + lg * 8;
    const unsigned short* bp1 = bp0 + (16 << 8);
#pragma unroll
    for (int kf = 0; kf < 8; ++kf) {
      short8 tA = *(const short8*)(apBase + kf * 32);
      short8 av0 = *(const short8*)(bp0 + kf * 32);
      short8 av1 = *(const short8*)(bp1 + kf * 32);
      short8 sw = rot16x4(tA);
      ac0 = __builtin_amdgcn_mfma_f32_16x16x32_bf16(av0, tA, ac0, 0, 0, 0);
      ac1 = __builtin_amdgcn_mfma_f32_16x16x32_bf16(av1, tA, ac1, 0, 0, 0);
      ac0 = __builtin_amdgcn_mfma_f32_16x16x32_bf16(av0, sw, ac0, 0, 0, 0);
      ac1 = __builtin_amdgcn_mfma_f32_16x16x32_bf16(av1, sw, ac1, 0, 0, 0);
    }
    // ---- softmax (r13-verified; mRun per n=lm, uniform across lg)
    const float mOld = mRun;
    float tm = fmaxf(fmaxf(fmaxf(ac0[0], ac0[1]), fmaxf(ac0[2], ac0[3])),
                     fmaxf(fmaxf(ac1[0], ac1[1]), fmaxf(ac1[2], ac1[3])));
    tm = fmaxf(tm, __shfl_xor(tm, 16));
    tm = fmaxf(tm, __shfl_xor(tm, 32));
    const float mNew = fmaxf(mOld, tm);
    const float scale = __expf(mOld - mNew);
    float p0 = __expf(ac0[0] - mNew), p1 = __expf(ac0[1] - mNew);
    float p2 = __expf(ac0[2] - mNew), p3 = __expf(ac0[3] - mNew);
    float q0 = __expf(ac1[0] - mNew), q1 = __expf(ac1[1] - mNew);
    float q2 = __expf(ac1[2] - mNew), q3 = __expf(ac1[3] - mNew);
    float cs = ((p0 + p1) + (p2 + p3)) + ((q0 + q1) + (q2 + q3));
    cs += __shfl_xor(cs, 16);
    cs += __shfl_xor(cs, 32);
    sRun = sRun * scale + cs;
    mRun = mNew;
    // ---- pack + permute into A-frag layout (r13-verified)
    unsigned int d0 = (unsigned int)f2bf_rne(p0) |
                      (((unsigned int)f2bf_rne(p1)) << 16);
    unsigned int d1 = (unsigned int)f2bf_rne(p2) |
                      (((unsigned int)f2bf_rne(p3)) << 16);
    unsigned int e0 = (unsigned int)f2bf_rne(q0) |
                      (((unsigned int)f2bf_rne(q1)) << 16);
    unsigned int e1 = (unsigned int)f2bf_rne(q2) |
                      (((unsigned int)f2bf_rne(q3)) << 16);
    unsigned int A0 = (unsigned int)__shfl((int)d0, src1);
    unsigned int A1 = (unsigned int)__shfl((int)d1, src1);
    unsigned int B0 = (unsigned int)__shfl((int)d0, src2);
    unsigned int B1 = (unsigned int)__shfl((int)d1, src2);
    unsigned int C0 = (unsigned int)__shfl((int)e0, src1);
    unsigned int C1 = (unsigned int)__shfl((int)e1, src1);
    unsigned int D0 = (unsigned int)__shfl((int)e0, src2);
    unsigned int D1 = (unsigned int)__shfl((int)e1, src2);
    uint4v pu;
    pu.x = hi2 ? C0 : A0;
    pu.y = hi2 ? C1 : A1;
    pu.z = hi2 ? D0 : B0;
    pu.w = hi2 ? D1 : B1;
    short8 pf = __builtin_bit_cast(short8, pu);
    // ---- online O-rescale (exact skip when no max growth anywhere)
    if (!__all(mNew == mOld)) {
      float s0 = __shfl(scale, rbase + 0);
      float s1 = __shfl(scale, rbase + 1);
      float s2 = __shfl(scale, rbase + 2);
      float s3 = __shfl(scale, rbase + 3);
#pragma unroll
      for (int ct = 0; ct < 13; ++ct) {
        oacc[ct][0] *= s0;
        oacc[ct][1] *= s1;
        oacc[ct][2] *= s2;
        oacc[ct][3] *= s3;
      }
    }
    // ---- PV: 13 c-tiles over this step's 32-m slice
    const unsigned short* gbase =
        gP + ((size_t)(b * 208) << 10) + m0 + lg * 8;
#pragma unroll
    for (int ct = 0; ct < 13; ++ct) {
      int c = (ct << 4) + lm;
      short8 gv = *(const short8*)(gbase + ((size_t)c << 10));
      oacc[ct] = __builtin_amdgcn_mfma_f32_16x16x32_bf16(pf, gv, oacc[ct], 0, 0, 0);
    }
  }

  // ---- stats to LDS (mRun/sRun uniform across lg; lane lm owns row n=lm)
  if (l < 16) {
    statsL[w][lm][0] = mRun;
    statsL[w][lm][1] = sRun;
  }
  __syncthreads();

  // merge the 4 quarter stats per row n
  if (t < 16) {
    float mF = -3.0e38f;
#pragma unroll
    for (int qq = 0; qq < 4; ++qq) mF = fmaxf(mF, statsL[qq][t][0]);
    float sF = 0.0f;
#pragma unroll
    for (int qq = 0; qq < 4; ++qq)
      sF += statsL[qq][t][1] * __expf(statsL[qq][t][0] - mF);
    mFinL[t] = mF;
    invL[t] = 1.0f / sF;
  }
  __syncthreads();

  // ---- final per-wave correction, in-register
  {
    float corrMe = __expf(mRun - mFinL[lm]) * invL[lm];
    float c0 = __shfl(corrMe, rbase + 0);
    float c1 = __shfl(corrMe, rbase + 1);
    float c2 = __shfl(corrMe, rbase + 2);
    float c3 = __shfl(corrMe, rbase + 3);
#pragma unroll
    for (int ct = 0; ct < 13; ++ct) {
      oacc[ct][0] *= c0;
      oacc[ct][1] *= c1;
      oacc[ct][2] *= c2;
      oacc[ct][3] *= c3;
    }
  }

  // ---- cross-wave reduce (r13-verified serial 4-round)
  for (int rnd = 0; rnd < 4; ++rnd) {
    if (w == rnd) {
#pragma unroll
      for (int ct = 0; ct < 13; ++ct) {
#pragma unroll
        for (int r = 0; r < 4; ++r) {
          int n = rbase + r;
          int c = (ct << 4) + lm;
          if (rnd == 0) outAcc[n][c] = oacc[ct][r];
          else outAcc[n][c] += oacc[ct][r];
        }
      }
    }
    __syncthreads();
  }

  // final write: 16 threads per c write 16 consecutive n (64B lines)
  {
    int lane16 = t & 15;
    int grp = t >> 4;
    for (int c = grp; c < 200; c += 16)
      out[(((size_t)(b * 200 + c)) << 12) + n0 + lane16] = outAcc[lane16][c];
  }
}

// ---------------------------------------------------------------------------
extern "C" void kernel_launch(void* const* d_in, const int* in_sizes, int n_in,
                              void* d_out, int out_size, void* d_ws,
                              size_t ws_size, hipStream_t stream) {
  const float* x  = (const float*)d_in[0];
  const float* tw = (const float*)d_in[1];
  const float* tb = (const float*)d_in[2];
  const float* pw = (const float*)d_in[3];
  const float* pb = (const float*)d_in[4];
  const float* gw = (const float*)d_in[5];
  const float* gb = (const float*)d_in[6];
  float* out = (float*)d_out;

  unsigned short* ws_us = (unsigned short*)d_ws;
  unsigned short* thd   = ws_us;               //  8,388,608 us
  unsigned short* phd   = ws_us + 8388608;     //  2,097,152
  unsigned short* gP    = ws_us + 10485760;    //  1,703,936
  unsigned short* xTi   = ws_us + 12189696;    //  5,017,600
  unsigned short* wTi   = ws_us + 17207296;    //  2,809,856
  unsigned short* xTi_h = ws_us + 20017152;    //  2,508,800
  unsigned short* wTi_s = ws_us + 22525952;    //    602,112
  float* biasPad = (float*)(ws_us + 23128064); //  448 f  (~46.3 MB total)

  prep_x<<<560, 256, 0, stream>>>(x, (unsigned int*)xTi, (unsigned int*)xTi_h);
  prep_w<<<6664, 256, 0, stream>>>(tw, pw, gw, tb, pb, gb,
                                   (unsigned int*)wTi, (unsigned int*)wTi_s,
                                   biasPad);

  convmfma_kernel<true><<<dim3(64, 4), 256, 0, stream>>>(
      xTi, wTi, biasPad, (unsigned int*)thd, (unsigned int*)phd, gP);
  convmfma_kernel<false><<<dim3(64, 3), 256, 0, stream>>>(
      xTi_h, wTi_s, biasPad, (unsigned int*)thd, (unsigned int*)phd, gP);
  attn_kernel<<<2048, 256, 0, stream>>>(thd, phd, gP, out);
}

// Round 18
// 446.073 us; speedup vs baseline: 1.1242x; 1.1242x over previous
//
#include <hip/hip_runtime.h>
#include <cstdint>
#include <cstddef>

#define BATCH 8
#define CIN 64
#define HIN 70
#define HOUT 64
#define NPIX 4096
#define MPIX 1024

typedef __attribute__((ext_vector_type(8))) short short8;
typedef __attribute__((ext_vector_type(4))) float f32x4;
typedef __attribute__((ext_vector_type(4))) unsigned int uint4v;

__device__ __forceinline__ unsigned short f2bf_rne(float f) {
  unsigned int u = __builtin_bit_cast(unsigned int, f);
  unsigned int r = (u + 0x7FFFu + ((u >> 16) & 1u)) >> 16;
  return (unsigned short)r;
}

__device__ __forceinline__ unsigned int rot16(unsigned int u) {
  return (u >> 16) | (u << 16);
}

__device__ __forceinline__ short8 rot16x4(short8 v) {
  uint4v u = __builtin_bit_cast(uint4v, v);
  u.x = rot16(u.x); u.y = rot16(u.y); u.z = rot16(u.z); u.w = rot16(u.w);
  return __builtin_bit_cast(short8, u);
}

// ---------------------------------------------------------------------------
// prep_x: x -> xTi [8][70][70][128us] dual (hi,lo) pairs
//            + xTi_h [8][70][70][64us] hi-only (for single-bf16 g path)
// ---------------------------------------------------------------------------
__global__ __launch_bounds__(256) void prep_x(const float* __restrict__ x,
                                              unsigned int* __restrict__ xTi,
                                              unsigned int* __restrict__ xTi_h) {
  __shared__ float tile[64][71];
  const int blk = blockIdx.x;  // 0..559
  const int b = blk / 70;
  const int r = blk - b * 70;
  const int t = threadIdx.x;
  for (int i = t; i < 64 * 70; i += 256) {
    int ci = i / 70;
    int c = i - ci * 70;
    tile[ci][c] = x[(((size_t)(b * 64 + ci)) * 70 + r) * 70 + c];
  }
  __syncthreads();
  for (int i = t; i < 70 * 64; i += 256) {
    int c = i >> 6;
    int ci = i & 63;
    float a = tile[ci][c];
    unsigned short hi = f2bf_rne(a);
    float hif = __builtin_bit_cast(float, ((unsigned int)hi) << 16);
    unsigned short lo = f2bf_rne(a - hif);
    xTi[(((size_t)(b * 70 + r)) * 70 + c) * 64 + ci] =
        (unsigned int)hi | (((unsigned int)lo) << 16);
  }
  for (int i = t; i < 70 * 32; i += 256) {
    int c = i >> 5;
    int dwi = i & 31;
    unsigned int h0 = f2bf_rne(tile[2 * dwi][c]);
    unsigned int h1 = f2bf_rne(tile[2 * dwi + 1][c]);
    xTi_h[(((size_t)(b * 70 + r)) * 70 + c) * 32 + dwi] = h0 | (h1 << 16);
  }
}

// ---------------------------------------------------------------------------
// prep_w: wTi [49][448][64dw] dual pairs + biasPad[448]
//         wTi_s [49][192][32dw] hi-only (OC 256..447 = g[56..199] + pad)
// ---------------------------------------------------------------------------
__global__ __launch_bounds__(256) void prep_w(
    const float* __restrict__ tw, const float* __restrict__ pw,
    const float* __restrict__ gw,
    const float* __restrict__ tb, const float* __restrict__ pb,
    const float* __restrict__ gb,
    unsigned int* __restrict__ wTi, unsigned int* __restrict__ wTi_s,
    float* __restrict__ biasPad) {
  int gid = blockIdx.x * 256 + threadIdx.x;
  if (gid < 1404928) {  // 49*448*64 dual dwords
    if (gid < 448) {
      float bv = 0.0f;
      if (gid < 100) bv = tb[gid];
      else if (gid < 200) bv = pb[gid - 100];
      else if (gid < 400) bv = gb[gid - 200];
      biasPad[gid] = bv;
    }
    int ci = gid & 63;
    int OC = (gid >> 6) % 448;
    int s = gid / (448 * 64);
    float v = 0.0f;
    if (OC < 100) v = tw[((size_t)(OC * 64 + ci)) * 49 + s];
    else if (OC < 200) v = pw[((size_t)((OC - 100) * 64 + ci)) * 49 + s];
    else if (OC < 400) v = gw[((size_t)((OC - 200) * 64 + ci)) * 49 + s];
    unsigned short hi = f2bf_rne(v);
    float hif = __builtin_bit_cast(float, ((unsigned int)hi) << 16);
    unsigned short lo = f2bf_rne(v - hif);
    wTi[gid] = (unsigned int)hi | (((unsigned int)lo) << 16);
  } else if (gid < 1404928 + 301056) {  // 49*192*32 single dwords
    int g2 = gid - 1404928;
    int dwi = g2 & 31;
    int OCl = (g2 >> 5) % 192;
    int s = g2 / (192 * 32);
    int gc = 56 + OCl;
    float v0 = 0.0f, v1 = 0.0f;
    if (gc < 200) {
      v0 = gw[((size_t)(gc * 64 + 2 * dwi)) * 49 + s];
      v1 = gw[((size_t)(gc * 64 + 2 * dwi + 1)) * 49 + s];
    }
    wTi_s[g2] = (unsigned int)f2bf_rne(v0) |
                (((unsigned int)f2bf_rne(v1)) << 16);
  }
}

// ---------------------------------------------------------------------------
// convmfma v6 (unchanged from r13, verified): 256-thr / 4-wave, wave = 2 rows
// ---------------------------------------------------------------------------
template <bool DUAL>
__global__ __launch_bounds__(256, 2) void convmfma_kernel(
    const unsigned short* __restrict__ xT,
    const unsigned short* __restrict__ wT,
    const float* __restrict__ biasPad,
    unsigned int* __restrict__ thd_dw,
    unsigned int* __restrict__ phd_dw,
    unsigned short* __restrict__ gP) {
  __shared__ __align__(16) char smem[62720 + 16384];
  const int LDSW = 62720;
  const int NCH = DUAL ? 4 : 2;
  const int XS = DUAL ? 128 : 64;
  const int WOCS = DUAL ? 128 : 64;
  const int WSTRIDE = DUAL ? 57344 : 12288;

  const int gx = blockIdx.x;
  const int b = gx >> 3;
  const int ptile = gx & 7;
  const int oy0 = ptile * 8;
  const int oc0 = (DUAL ? 0 : 256) + (blockIdx.y << 6);
  const int oc0W = DUAL ? oc0 : (blockIdx.y << 6);

  const int t = threadIdx.x;
  const int wv = t >> 6;
  const int l = t & 63;
  const int lm = l & 15;
  const int lg = l >> 4;

  int wdstOff_[2];
  const unsigned short* wsrc_[2];
  const int keyA = ((lm >> 1) & 3) << 4;
  const int laneA = (lm << 6) + ((lg << 4) ^ keyA);

  f32x4 acc[4][2][4];
#pragma unroll
  for (int j = 0; j < 4; ++j)
#pragma unroll
    for (int rr = 0; rr < 2; ++rr)
#pragma unroll
      for (int f = 0; f < 4; ++f) acc[j][rr][f] = (f32x4)0.0f;

  for (int chunk = 0; chunk < NCH; ++chunk) {
    for (int i = t; i < 3920; i += 256) {
      int idx70 = i >> 2;
      int s16 = i & 3;
      int rr = idx70 / 70;
      int cc = idx70 - rr * 70;
      const unsigned short* src =
          xT + ((size_t)((b * 70 + oy0 + rr) * 70 + cc)) * XS +
          (chunk << 5) + (s16 << 3);
      short8 v = *(const short8*)src;
      int dst = (idx70 << 6) + ((s16 << 4) ^ (((cc >> 1) & 3) << 4));
      *(short8*)(smem + dst) = v;
    }
    short8 wreg[2];
#pragma unroll
    for (int u2 = 0; u2 < 2; ++u2) {
      int u = t + (u2 << 8);
      int sub = u >> 8;
      int oc_t = (u >> 2) & 63;
      int q = u & 3;
      wdstOff_[u2] =
          sub * 4096 + (oc_t << 6) + ((q << 4) ^ (((oc_t >> 1) & 3) << 4));
      wsrc_[u2] = wT + (size_t)(oc0W + oc_t) * WOCS + (chunk << 5) + (q << 3);
      wreg[u2] = *(const short8*)(wsrc_[u2] + (size_t)sub * WSTRIDE);
      *(short8*)(smem + LDSW + wdstOff_[u2]) = wreg[u2];
      wreg[u2] = *(const short8*)(wsrc_[u2] + (size_t)(2 + sub) * WSTRIDE);
    }
    __syncthreads();

    for (int p = 0; p < 25; ++p) {
      const char* slotBase = smem + LDSW + ((p & 1) << 13);
#pragma unroll
      for (int halfs = 0; halfs < 2; ++halfs) {
        const int s = 2 * p + halfs;
        if (s <= 48) {
          const int ky = s / 7;
          const int kx = s - ky * 7;
          const char* wb = slotBase + (halfs << 12) + laneA;
          short8 aW[4], aS[4];
#pragma unroll
          for (int j = 0; j < 4; ++j) {
            aW[j] = *(const short8*)(wb + j * 1024);
            if (DUAL) aS[j] = rot16x4(aW[j]);
          }
          const int klx = kx + lm;
          const int key = ((klx >> 1) & 3) << 4;
#pragma unroll
          for (int rr = 0; rr < 2; ++rr) {
            const char* bbase =
                smem + ((2 * wv + rr + ky) * 70 + klx) * 64 + ((lg << 4) ^ key);
#pragma unroll
            for (int f = 0; f < 4; ++f) {
              short8 bf = *(const short8*)(bbase + f * 1024);
#pragma unroll
              for (int j = 0; j < 4; ++j) {
                acc[j][rr][f] = __builtin_amdgcn_mfma_f32_16x16x32_bf16(
                    aW[j], bf, acc[j][rr][f], 0, 0, 0);
                if (DUAL)
                  acc[j][rr][f] = __builtin_amdgcn_mfma_f32_16x16x32_bf16(
                      aS[j], bf, acc[j][rr][f], 0, 0, 0);
              }
            }
          }
        }
      }
      if (p < 24) {
#pragma unroll
        for (int u2 = 0; u2 < 2; ++u2) {
          *(short8*)(smem + LDSW + (((p + 1) & 1) << 13) + wdstOff_[u2]) =
              wreg[u2];
          if (p < 23) {
            int sub = (t + (u2 << 8)) >> 8;
            int snext = 2 * (p + 2) + sub;
            if (snext > 48) snext = 48;
            wreg[u2] = *(const short8*)(wsrc_[u2] + (size_t)snext * WSTRIDE);
          }
        }
      }
      __syncthreads();
    }
  }

  float bia[4][4];
#pragma unroll
  for (int j = 0; j < 4; ++j)
#pragma unroll
    for (int r = 0; r < 4; ++r) bia[j][r] = biasPad[oc0 + j * 16 + lg * 4 + r];

  if (DUAL) {
#pragma unroll
    for (int j = 0; j < 4; ++j) {
#pragma unroll
      for (int rr = 0; rr < 2; ++rr) {
#pragma unroll
        for (int f = 0; f < 4; ++f) {
#pragma unroll
          for (int r = 0; r < 4; ++r) {
            int ch = oc0 + j * 16 + lg * 4 + r;
            if (ch < 128) {
              int n = (oy0 + 2 * wv + rr) * 64 + f * 16 + lm;
              unsigned int outw = 0u;
              if (ch < 100) {
                float v = acc[j][rr][f][r] + bia[j][r];
                unsigned short hi = f2bf_rne(v);
                float hif =
                    __builtin_bit_cast(float, ((unsigned int)hi) << 16);
                unsigned short lo = f2bf_rne(v - hif);
                outw = (unsigned int)hi | (((unsigned int)lo) << 16);
              }
              thd_dw[(((size_t)(b << 12) + n) << 7) + ch] = outw;
            }
          }
        }
      }
    }
  }

#pragma unroll
  for (int j = 0; j < 4; ++j) {
#pragma unroll
    for (int f = 0; f < 4; ++f) {
#pragma unroll
      for (int r = 0; r < 4; ++r) {
        float v0 = acc[j][0][f][r] + bia[j][r];
        float v1 = acc[j][1][f][r] + bia[j][r];
        float vr = fmaxf(v0, v1);
        float vn = fmaxf(vr, __shfl_xor(vr, 1));
        if (!(lm & 1)) {
          int ch = oc0 + j * 16 + lg * 4 + r;
          int m = (((oy0 >> 1) + wv) << 5) + f * 8 + (lm >> 1);
          if (DUAL) {
            if (ch >= 100 && ch < 200) {
              int c = ch - 100;
              unsigned short hi = f2bf_rne(vn);
              float hif = __builtin_bit_cast(float, ((unsigned int)hi) << 16);
              unsigned short lo = f2bf_rne(vn - hif);
              phd_dw[(((size_t)(b << 10) + m) << 7) + c] =
                  (unsigned int)hi | (((unsigned int)lo) << 16);
            } else if (ch >= 200) {
              gP[((size_t)(b * 208 + (ch - 200)) << 10) + m] = f2bf_rne(vn);
              if (ch < 228)
                phd_dw[(((size_t)(b << 10) + m) << 7) + (ch - 100)] = 0u;
            }
          } else {
            int cg = ch - 200;
            if (cg < 208)
              gP[((size_t)(b * 208 + cg) << 10) + m] = f2bf_rne(vn);
          }
        }
      }
    }
  }
}

// ---------------------------------------------------------------------------
// attn v3-xcd: EXACT r13 attn kernel (verified best, 229.7us) plus:
//  (1) batch->XCD block swizzle: XCD i gets exactly batch i's 256 tiles so
//      phi/g (928KB/batch) stay resident in ONE XCD's 4MB L2 instead of
//      being duplicated+thrashed across all 8.
//  (2) s_setprio(1) around the two MFMA clusters (T5, +4-7% on attn).
// ---------------------------------------------------------------------------
__global__ __launch_bounds__(256) void attn_kernel(
    const unsigned short* __restrict__ thd,  // [8][4096][256]
    const unsigned short* __restrict__ phd,  // [8][1024][256]
    const unsigned short* __restrict__ gP,   // [8][208][1024]
    float* __restrict__ out) {               // [8][200][4096]
  __shared__ __align__(16) float outAcc[16][212];
  __shared__ float corrL[16][33];
  __shared__ float statsL[4][16][2];
  __shared__ float mFinL[16];
  __shared__ float invL[16];

  // batch->XCD swizzle: dispatch round-robins blockIdx%8 across XCDs, so
  // assign batch = blockIdx%8. 2048 % 8 == 0 -> bijective.
  const int bid = blockIdx.x;  // 0..2047
  const int b = bid & 7;
  const int n0 = (bid >> 3) << 4;
  const int t = threadIdx.x;
  const int w = t >> 6;        // m-quarter 0..3
  const int l = t & 63;
  const int lm = l & 15;
  const int lg = l >> 4;

  // theta frags (B-operand: col n = n0+lm, k-slice lg) + pair-swapped copy
  short8 aA[8], aS[8];
  {
    const unsigned short* ap =
        thd + (((size_t)(b << 12) + n0 + lm) << 8) + lg * 8;
#pragma unroll
    for (int kf = 0; kf < 8; ++kf) {
      short8 v = *(const short8*)(ap + kf * 32);
      aA[kf] = v;
      aS[kf] = rot16x4(v);
    }
  }

  float mRun = -3.0e38f, sRun = 0.0f;
  unsigned int Pr[8][4];

  const int src1 = ((lg & 1) << 5) + lm;
  const int src2 = src1 + 16;
  const bool hi2 = (lg >> 1) != 0;

#pragma unroll
  for (int step = 0; step < 8; ++step) {
    const int m0 = (w << 8) + (step << 5);
    f32x4 ac0 = (f32x4)0.f, ac1 = (f32x4)0.f;
    const unsigned short* bp0 =
        phd + (((size_t)(b << 10) + m0 + lm) << 8) + lg * 8;
    const unsigned short* bp1 = bp0 + (16 << 8);
    __builtin_amdgcn_s_setprio(1);
#pragma unroll
    for (int kf = 0; kf < 8; ++kf) {
      short8 av0 = *(const short8*)(bp0 + kf * 32);
      short8 av1 = *(const short8*)(bp1 + kf * 32);
      ac0 = __builtin_amdgcn_mfma_f32_16x16x32_bf16(av0, aA[kf], ac0, 0, 0, 0);
      ac1 = __builtin_amdgcn_mfma_f32_16x16x32_bf16(av1, aA[kf], ac1, 0, 0, 0);
      ac0 = __builtin_amdgcn_mfma_f32_16x16x32_bf16(av0, aS[kf], ac0, 0, 0, 0);
      ac1 = __builtin_amdgcn_mfma_f32_16x16x32_bf16(av1, aS[kf], ac1, 0, 0, 0);
    }
    __builtin_amdgcn_s_setprio(0);
    // softmax over m-chunk (n fixed per lane); reduce over 4 lg-lanes
    float tm = fmaxf(fmaxf(fmaxf(ac0[0], ac0[1]), fmaxf(ac0[2], ac0[3])),
                     fmaxf(fmaxf(ac1[0], ac1[1]), fmaxf(ac1[2], ac1[3])));
    tm = fmaxf(tm, __shfl_xor(tm, 16));
    tm = fmaxf(tm, __shfl_xor(tm, 32));
    float mNew = fmaxf(mRun, tm);
    float scale = __expf(mRun - mNew);
    float p0 = __expf(ac0[0] - mNew), p1 = __expf(ac0[1] - mNew);
    float p2 = __expf(ac0[2] - mNew), p3 = __expf(ac0[3] - mNew);
    float q0 = __expf(ac1[0] - mNew), q1 = __expf(ac1[1] - mNew);
    float q2 = __expf(ac1[2] - mNew), q3 = __expf(ac1[3] - mNew);
    float cs = ((p0 + p1) + (p2 + p3)) + ((q0 + q1) + (q2 + q3));
    cs += __shfl_xor(cs, 16);
    cs += __shfl_xor(cs, 32);
    mRun = mNew;
    sRun = sRun * scale + cs;
    if (l < 16) corrL[lm][(w << 3) + step] = mRun;
    // pack to bf16 dwords
    unsigned int d0 = (unsigned int)f2bf_rne(p0) |
                      (((unsigned int)f2bf_rne(p1)) << 16);
    unsigned int d1 = (unsigned int)f2bf_rne(p2) |
                      (((unsigned int)f2bf_rne(p3)) << 16);
    unsigned int e0 = (unsigned int)f2bf_rne(q0) |
                      (((unsigned int)f2bf_rne(q1)) << 16);
    unsigned int e1 = (unsigned int)f2bf_rne(q2) |
                      (((unsigned int)f2bf_rne(q3)) << 16);
    // lane permute into A-frag layout: lane lg gets m = m0 + lg*8 + 0..7
    unsigned int A0 = (unsigned int)__shfl((int)d0, src1);
    unsigned int A1 = (unsigned int)__shfl((int)d1, src1);
    unsigned int B0 = (unsigned int)__shfl((int)d0, src2);
    unsigned int B1 = (unsigned int)__shfl((int)d1, src2);
    unsigned int C0 = (unsigned int)__shfl((int)e0, src1);
    unsigned int C1 = (unsigned int)__shfl((int)e1, src1);
    unsigned int D0 = (unsigned int)__shfl((int)e0, src2);
    unsigned int D1 = (unsigned int)__shfl((int)e1, src2);
    Pr[step][0] = hi2 ? C0 : A0;
    Pr[step][1] = hi2 ? C1 : A1;
    Pr[step][2] = hi2 ? D0 : B0;
    Pr[step][3] = hi2 ? D1 : B1;
  }
  if (l < 16) {
    statsL[w][lm][0] = mRun;
    statsL[w][lm][1] = sRun;
  }
  __syncthreads();

  // merge the 4 quarter stats per row
  if (t < 16) {
    float mF = -3.0e38f;
#pragma unroll
    for (int qq = 0; qq < 4; ++qq) mF = fmaxf(mF, statsL[qq][t][0]);
    float sF = 0.0f;
#pragma unroll
    for (int qq = 0; qq < 4; ++qq)
      sF += statsL[qq][t][1] * __expf(statsL[qq][t][0] - mF);
    mFinL[t] = mF;
    invL[t] = 1.0f / sF;
  }
  __syncthreads();

  // m_used -> correction factors, 1/sum folded in
  {
    int e = t * 2;
#pragma unroll
    for (int i = 0; i < 2; ++i) {
      int row = (e + i) >> 5;
      int col = (e + i) & 31;
      corrL[row][col] = __expf(corrL[row][col] - mFinL[row]) * invL[row];
    }
  }
  __syncthreads();

  // in-register rescale of P
#pragma unroll
  for (int s = 0; s < 8; ++s) {
    float corr = corrL[lm][(w << 3) + s];
#pragma unroll
    for (int j = 0; j < 4; ++j) {
      unsigned int u = Pr[s][j];
      float lo = __builtin_bit_cast(float, u << 16);
      float hi = __builtin_bit_cast(float, u & 0xffff0000u);
      Pr[s][j] = (unsigned int)f2bf_rne(lo * corr) |
                 (((unsigned int)f2bf_rne(hi * corr)) << 16);
    }
  }

  // Phase C: partial over this wave's m-quarter, all 13 c-tiles
  f32x4 oacc[13];
#pragma unroll
  for (int i = 0; i < 13; ++i) oacc[i] = (f32x4)0.f;

  __builtin_amdgcn_s_setprio(1);
#pragma unroll
  for (int s = 0; s < 8; ++s) {
    uint4v pu;
    pu.x = Pr[s][0]; pu.y = Pr[s][1]; pu.z = Pr[s][2]; pu.w = Pr[s][3];
    short8 pf = __builtin_bit_cast(short8, pu);
    const unsigned short* gbase =
        gP + ((size_t)(b * 208) << 10) + (w << 8) + (s << 5) + lg * 8;
#pragma unroll
    for (int ct = 0; ct < 13; ++ct) {
      int c = (ct << 4) + lm;
      short8 gv = *(const short8*)(gbase + ((size_t)c << 10));
      oacc[ct] = __builtin_amdgcn_mfma_f32_16x16x32_bf16(pf, gv, oacc[ct], 0, 0, 0);
    }
  }
  __builtin_amdgcn_s_setprio(0);

  // cross-wave reduce through LDS (4 rounds)
  for (int rnd = 0; rnd < 4; ++rnd) {
    if (w == rnd) {
#pragma unroll
      for (int ct = 0; ct < 13; ++ct) {
#pragma unroll
        for (int r = 0; r < 4; ++r) {
          int n = (lg << 2) + r;
          int c = (ct << 4) + lm;
          if (rnd == 0) outAcc[n][c] = oacc[ct][r];
          else outAcc[n][c] += oacc[ct][r];
        }
      }
    }
    __syncthreads();
  }

  // final write: 16 threads per c write 16 consecutive n (64B lines)
  {
    int lane16 = t & 15;
    int grp = t >> 4;
    for (int c = grp; c < 200; c += 16)
      out[(((size_t)(b * 200 + c)) << 12) + n0 + lane16] = outAcc[lane16][c];
  }
}

// ---------------------------------------------------------------------------
extern "C" void kernel_launch(void* const* d_in, const int* in_sizes, int n_in,
                              void* d_out, int out_size, void* d_ws,
                              size_t ws_size, hipStream_t stream) {
  const float* x  = (const float*)d_in[0];
  const float* tw = (const float*)d_in[1];
  const float* tb = (const float*)d_in[2];
  const float* pw = (const float*)d_in[3];
  const float* pb = (const float*)d_in[4];
  const float* gw = (const float*)d_in[5];
  const float* gb = (const float*)d_in[6];
  float* out = (float*)d_out;

  unsigned short* ws_us = (unsigned short*)d_ws;
  unsigned short* thd   = ws_us;               //  8,388,608 us
  unsigned short* phd   = ws_us + 8388608;     //  2,097,152
  unsigned short* gP    = ws_us + 10485760;    //  1,703,936
  unsigned short* xTi   = ws_us + 12189696;    //  5,017,600
  unsigned short* wTi   = ws_us + 17207296;    //  2,809,856
  unsigned short* xTi_h = ws_us + 20017152;    //  2,508,800
  unsigned short* wTi_s = ws_us + 22525952;    //    602,112
  float* biasPad = (float*)(ws_us + 23128064); //  448 f  (~46.3 MB total)

  prep_x<<<560, 256, 0, stream>>>(x, (unsigned int*)xTi, (unsigned int*)xTi_h);
  prep_w<<<6664, 256, 0, stream>>>(tw, pw, gw, tb, pb, gb,
                                   (unsigned int*)wTi, (unsigned int*)wTi_s,
                                   biasPad);

  convmfma_kernel<true><<<dim3(64, 4), 256, 0, stream>>>(
      xTi, wTi, biasPad, (unsigned int*)thd, (unsigned int*)phd, gP);
  convmfma_kernel<false><<<dim3(64, 3), 256, 0, stream>>>(
      xTi_h, wTi_s, biasPad, (unsigned int*)thd, (unsigned int*)phd, gP);
  attn_kernel<<<2048, 256, 0, stream>>>(thd, phd, gP, out);
}

// Round 19
// 414.166 us; speedup vs baseline: 1.2108x; 1.0770x over previous
//
#include <hip/hip_runtime.h>
#include <cstdint>
#include <cstddef>

#define BATCH 8
#define CIN 64
#define HIN 70
#define HOUT 64
#define NPIX 4096
#define MPIX 1024

typedef __attribute__((ext_vector_type(8))) short short8;
typedef __attribute__((ext_vector_type(4))) float f32x4;
typedef __attribute__((ext_vector_type(4))) unsigned int uint4v;

__device__ __forceinline__ unsigned short f2bf_rne(float f) {
  unsigned int u = __builtin_bit_cast(unsigned int, f);
  unsigned int r = (u + 0x7FFFu + ((u >> 16) & 1u)) >> 16;
  return (unsigned short)r;
}

__device__ __forceinline__ unsigned int rot16(unsigned int u) {
  return (u >> 16) | (u << 16);
}

__device__ __forceinline__ short8 rot16x4(short8 v) {
  uint4v u = __builtin_bit_cast(uint4v, v);
  u.x = rot16(u.x); u.y = rot16(u.y); u.z = rot16(u.z); u.w = rot16(u.w);
  return __builtin_bit_cast(short8, u);
}

// ---------------------------------------------------------------------------
// prep_x: x -> xTi [8][70][70][128us] dual (hi,lo) pairs
//            + xTi_h [8][70][70][64us] hi-only (for single-bf16 g path)
// ---------------------------------------------------------------------------
__global__ __launch_bounds__(256) void prep_x(const float* __restrict__ x,
                                              unsigned int* __restrict__ xTi,
                                              unsigned int* __restrict__ xTi_h) {
  __shared__ float tile[64][71];
  const int blk = blockIdx.x;  // 0..559
  const int b = blk / 70;
  const int r = blk - b * 70;
  const int t = threadIdx.x;
  for (int i = t; i < 64 * 70; i += 256) {
    int ci = i / 70;
    int c = i - ci * 70;
    tile[ci][c] = x[(((size_t)(b * 64 + ci)) * 70 + r) * 70 + c];
  }
  __syncthreads();
  for (int i = t; i < 70 * 64; i += 256) {
    int c = i >> 6;
    int ci = i & 63;
    float a = tile[ci][c];
    unsigned short hi = f2bf_rne(a);
    float hif = __builtin_bit_cast(float, ((unsigned int)hi) << 16);
    unsigned short lo = f2bf_rne(a - hif);
    xTi[(((size_t)(b * 70 + r)) * 70 + c) * 64 + ci] =
        (unsigned int)hi | (((unsigned int)lo) << 16);
  }
  for (int i = t; i < 70 * 32; i += 256) {
    int c = i >> 5;
    int dwi = i & 31;
    unsigned int h0 = f2bf_rne(tile[2 * dwi][c]);
    unsigned int h1 = f2bf_rne(tile[2 * dwi + 1][c]);
    xTi_h[(((size_t)(b * 70 + r)) * 70 + c) * 32 + dwi] = h0 | (h1 << 16);
  }
}

// ---------------------------------------------------------------------------
// prep_w: wTi [49][448][64dw] dual pairs + biasPad[448]
//         wTi_s [49][192][32dw] hi-only (OC 256..447 = g[56..199] + pad)
// ---------------------------------------------------------------------------
__global__ __launch_bounds__(256) void prep_w(
    const float* __restrict__ tw, const float* __restrict__ pw,
    const float* __restrict__ gw,
    const float* __restrict__ tb, const float* __restrict__ pb,
    const float* __restrict__ gb,
    unsigned int* __restrict__ wTi, unsigned int* __restrict__ wTi_s,
    float* __restrict__ biasPad) {
  int gid = blockIdx.x * 256 + threadIdx.x;
  if (gid < 1404928) {  // 49*448*64 dual dwords
    if (gid < 448) {
      float bv = 0.0f;
      if (gid < 100) bv = tb[gid];
      else if (gid < 200) bv = pb[gid - 100];
      else if (gid < 400) bv = gb[gid - 200];
      biasPad[gid] = bv;
    }
    int ci = gid & 63;
    int OC = (gid >> 6) % 448;
    int s = gid / (448 * 64);
    float v = 0.0f;
    if (OC < 100) v = tw[((size_t)(OC * 64 + ci)) * 49 + s];
    else if (OC < 200) v = pw[((size_t)((OC - 100) * 64 + ci)) * 49 + s];
    else if (OC < 400) v = gw[((size_t)((OC - 200) * 64 + ci)) * 49 + s];
    unsigned short hi = f2bf_rne(v);
    float hif = __builtin_bit_cast(float, ((unsigned int)hi) << 16);
    unsigned short lo = f2bf_rne(v - hif);
    wTi[gid] = (unsigned int)hi | (((unsigned int)lo) << 16);
  } else if (gid < 1404928 + 301056) {  // 49*192*32 single dwords
    int g2 = gid - 1404928;
    int dwi = g2 & 31;
    int OCl = (g2 >> 5) % 192;
    int s = g2 / (192 * 32);
    int gc = 56 + OCl;
    float v0 = 0.0f, v1 = 0.0f;
    if (gc < 200) {
      v0 = gw[((size_t)(gc * 64 + 2 * dwi)) * 49 + s];
      v1 = gw[((size_t)(gc * 64 + 2 * dwi + 1)) * 49 + s];
    }
    wTi_s[g2] = (unsigned int)f2bf_rne(v0) |
                (((unsigned int)f2bf_rne(v1)) << 16);
  }
}

// ---------------------------------------------------------------------------
// conv_body (r13-verified logic, verbatim; smem hoisted to wrapper).
// DUAL: theta/phi/g[0..55] dual-bf16.  !DUAL: g[56..199] single-bf16.
// ---------------------------------------------------------------------------
template <bool DUAL>
__device__ __forceinline__ void conv_body(
    char* smem, int ocy,
    const unsigned short* __restrict__ xT,
    const unsigned short* __restrict__ wT,
    const float* __restrict__ biasPad,
    unsigned int* __restrict__ thd_dw,
    unsigned int* __restrict__ phd_dw,
    unsigned short* __restrict__ gP) {
  const int LDSW = 62720;
  const int NCH = DUAL ? 4 : 2;
  const int XS = DUAL ? 128 : 64;
  const int WOCS = DUAL ? 128 : 64;
  const int WSTRIDE = DUAL ? 57344 : 12288;

  const int gx = blockIdx.x;
  const int b = gx >> 3;
  const int ptile = gx & 7;
  const int oy0 = ptile * 8;
  const int oc0 = (DUAL ? 0 : 256) + (ocy << 6);
  const int oc0W = DUAL ? oc0 : (ocy << 6);

  const int t = threadIdx.x;
  const int wv = t >> 6;
  const int l = t & 63;
  const int lm = l & 15;
  const int lg = l >> 4;

  int wdstOff_[2];
  const unsigned short* wsrc_[2];
  const int keyA = ((lm >> 1) & 3) << 4;
  const int laneA = (lm << 6) + ((lg << 4) ^ keyA);

  f32x4 acc[4][2][4];
#pragma unroll
  for (int j = 0; j < 4; ++j)
#pragma unroll
    for (int rr = 0; rr < 2; ++rr)
#pragma unroll
      for (int f = 0; f < 4; ++f) acc[j][rr][f] = (f32x4)0.0f;

  for (int chunk = 0; chunk < NCH; ++chunk) {
    for (int i = t; i < 3920; i += 256) {
      int idx70 = i >> 2;
      int s16 = i & 3;
      int rr = idx70 / 70;
      int cc = idx70 - rr * 70;
      const unsigned short* src =
          xT + ((size_t)((b * 70 + oy0 + rr) * 70 + cc)) * XS +
          (chunk << 5) + (s16 << 3);
      short8 v = *(const short8*)src;
      int dst = (idx70 << 6) + ((s16 << 4) ^ (((cc >> 1) & 3) << 4));
      *(short8*)(smem + dst) = v;
    }
    short8 wreg[2];
#pragma unroll
    for (int u2 = 0; u2 < 2; ++u2) {
      int u = t + (u2 << 8);
      int sub = u >> 8;
      int oc_t = (u >> 2) & 63;
      int q = u & 3;
      wdstOff_[u2] =
          sub * 4096 + (oc_t << 6) + ((q << 4) ^ (((oc_t >> 1) & 3) << 4));
      wsrc_[u2] = wT + (size_t)(oc0W + oc_t) * WOCS + (chunk << 5) + (q << 3);
      wreg[u2] = *(const short8*)(wsrc_[u2] + (size_t)sub * WSTRIDE);
      *(short8*)(smem + LDSW + wdstOff_[u2]) = wreg[u2];
      wreg[u2] = *(const short8*)(wsrc_[u2] + (size_t)(2 + sub) * WSTRIDE);
    }
    __syncthreads();

    for (int p = 0; p < 25; ++p) {
      const char* slotBase = smem + LDSW + ((p & 1) << 13);
#pragma unroll
      for (int halfs = 0; halfs < 2; ++halfs) {
        const int s = 2 * p + halfs;
        if (s <= 48) {
          const int ky = s / 7;
          const int kx = s - ky * 7;
          const char* wb = slotBase + (halfs << 12) + laneA;
          short8 aW[4], aS[4];
#pragma unroll
          for (int j = 0; j < 4; ++j) {
            aW[j] = *(const short8*)(wb + j * 1024);
            if (DUAL) aS[j] = rot16x4(aW[j]);
          }
          const int klx = kx + lm;
          const int key = ((klx >> 1) & 3) << 4;
#pragma unroll
          for (int rr = 0; rr < 2; ++rr) {
            const char* bbase =
                smem + ((2 * wv + rr + ky) * 70 + klx) * 64 + ((lg << 4) ^ key);
#pragma unroll
            for (int f = 0; f < 4; ++f) {
              short8 bf = *(const short8*)(bbase + f * 1024);
#pragma unroll
              for (int j = 0; j < 4; ++j) {
                acc[j][rr][f] = __builtin_amdgcn_mfma_f32_16x16x32_bf16(
                    aW[j], bf, acc[j][rr][f], 0, 0, 0);
                if (DUAL)
                  acc[j][rr][f] = __builtin_amdgcn_mfma_f32_16x16x32_bf16(
                      aS[j], bf, acc[j][rr][f], 0, 0, 0);
              }
            }
          }
        }
      }
      if (p < 24) {
#pragma unroll
        for (int u2 = 0; u2 < 2; ++u2) {
          *(short8*)(smem + LDSW + (((p + 1) & 1) << 13) + wdstOff_[u2]) =
              wreg[u2];
          if (p < 23) {
            int sub = (t + (u2 << 8)) >> 8;
            int snext = 2 * (p + 2) + sub;
            if (snext > 48) snext = 48;
            wreg[u2] = *(const short8*)(wsrc_[u2] + (size_t)snext * WSTRIDE);
          }
        }
      }
      __syncthreads();
    }
  }

  float bia[4][4];
#pragma unroll
  for (int j = 0; j < 4; ++j)
#pragma unroll
    for (int r = 0; r < 4; ++r) bia[j][r] = biasPad[oc0 + j * 16 + lg * 4 + r];

  if (DUAL) {
#pragma unroll
    for (int j = 0; j < 4; ++j) {
#pragma unroll
      for (int rr = 0; rr < 2; ++rr) {
#pragma unroll
        for (int f = 0; f < 4; ++f) {
#pragma unroll
          for (int r = 0; r < 4; ++r) {
            int ch = oc0 + j * 16 + lg * 4 + r;
            if (ch < 128) {
              int n = (oy0 + 2 * wv + rr) * 64 + f * 16 + lm;
              unsigned int outw = 0u;
              if (ch < 100) {
                float v = acc[j][rr][f][r] + bia[j][r];
                unsigned short hi = f2bf_rne(v);
                float hif =
                    __builtin_bit_cast(float, ((unsigned int)hi) << 16);
                unsigned short lo = f2bf_rne(v - hif);
                outw = (unsigned int)hi | (((unsigned int)lo) << 16);
              }
              thd_dw[(((size_t)(b << 12) + n) << 7) + ch] = outw;
            }
          }
        }
      }
    }
  }

#pragma unroll
  for (int j = 0; j < 4; ++j) {
#pragma unroll
    for (int f = 0; f < 4; ++f) {
#pragma unroll
      for (int r = 0; r < 4; ++r) {
        float v0 = acc[j][0][f][r] + bia[j][r];
        float v1 = acc[j][1][f][r] + bia[j][r];
        float vr = fmaxf(v0, v1);
        float vn = fmaxf(vr, __shfl_xor(vr, 1));
        if (!(lm & 1)) {
          int ch = oc0 + j * 16 + lg * 4 + r;
          int m = (((oy0 >> 1) + wv) << 5) + f * 8 + (lm >> 1);
          if (DUAL) {
            if (ch >= 100 && ch < 200) {
              int c = ch - 100;
              unsigned short hi = f2bf_rne(vn);
              float hif = __builtin_bit_cast(float, ((unsigned int)hi) << 16);
              unsigned short lo = f2bf_rne(vn - hif);
              phd_dw[(((size_t)(b << 10) + m) << 7) + c] =
                  (unsigned int)hi | (((unsigned int)lo) << 16);
            } else if (ch >= 200) {
              gP[((size_t)(b * 208 + (ch - 200)) << 10) + m] = f2bf_rne(vn);
              if (ch < 228)
                phd_dw[(((size_t)(b << 10) + m) << 7) + (ch - 100)] = 0u;
            }
          } else {
            int cg = ch - 200;
            if (cg < 208)
              gP[((size_t)(b * 208 + cg) << 10) + m] = f2bf_rne(vn);
          }
        }
      }
    }
  }
}

// ---------------------------------------------------------------------------
// convmfma merged: grid (64,7); y<4 -> DUAL tile y, else SINGLE tile y-4.
// Both variants co-resident across all 256 CUs (was 2 half-filled launches).
// ---------------------------------------------------------------------------
__global__ __launch_bounds__(256, 2) void convmfma_kernel(
    const unsigned short* __restrict__ xTi,
    const unsigned short* __restrict__ wTi,
    const unsigned short* __restrict__ xTi_h,
    const unsigned short* __restrict__ wTi_s,
    const float* __restrict__ biasPad,
    unsigned int* __restrict__ thd_dw,
    unsigned int* __restrict__ phd_dw,
    unsigned short* __restrict__ gP) {
  __shared__ __align__(16) char smem[62720 + 16384];
  if (blockIdx.y < 4)
    conv_body<true>(smem, blockIdx.y, xTi, wTi, biasPad, thd_dw, phd_dw, gP);
  else
    conv_body<false>(smem, blockIdx.y - 4, xTi_h, wTi_s, biasPad, thd_dw,
                     phd_dw, gP);
}

// ---------------------------------------------------------------------------
// attn (r18, tied-best 230us): r13 structure + batch->XCD swizzle + setprio
// ---------------------------------------------------------------------------
__global__ __launch_bounds__(256) void attn_kernel(
    const unsigned short* __restrict__ thd,  // [8][4096][256]
    const unsigned short* __restrict__ phd,  // [8][1024][256]
    const unsigned short* __restrict__ gP,   // [8][208][1024]
    float* __restrict__ out) {               // [8][200][4096]
  __shared__ __align__(16) float outAcc[16][212];
  __shared__ float corrL[16][33];
  __shared__ float statsL[4][16][2];
  __shared__ float mFinL[16];
  __shared__ float invL[16];

  const int bid = blockIdx.x;  // 0..2047
  const int b = bid & 7;
  const int n0 = (bid >> 3) << 4;
  const int t = threadIdx.x;
  const int w = t >> 6;
  const int l = t & 63;
  const int lm = l & 15;
  const int lg = l >> 4;

  short8 aA[8], aS[8];
  {
    const unsigned short* ap =
        thd + (((size_t)(b << 12) + n0 + lm) << 8) + lg * 8;
#pragma unroll
    for (int kf = 0; kf < 8; ++kf) {
      short8 v = *(const short8*)(ap + kf * 32);
      aA[kf] = v;
      aS[kf] = rot16x4(v);
    }
  }

  float mRun = -3.0e38f, sRun = 0.0f;
  unsigned int Pr[8][4];

  const int src1 = ((lg & 1) << 5) + lm;
  const int src2 = src1 + 16;
  const bool hi2 = (lg >> 1) != 0;

#pragma unroll
  for (int step = 0; step < 8; ++step) {
    const int m0 = (w << 8) + (step << 5);
    f32x4 ac0 = (f32x4)0.f, ac1 = (f32x4)0.f;
    const unsigned short* bp0 =
        phd + (((size_t)(b << 10) + m0 + lm) << 8) + lg * 8;
    const unsigned short* bp1 = bp0 + (16 << 8);
    __builtin_amdgcn_s_setprio(1);
#pragma unroll
    for (int kf = 0; kf < 8; ++kf) {
      short8 av0 = *(const short8*)(bp0 + kf * 32);
      short8 av1 = *(const short8*)(bp1 + kf * 32);
      ac0 = __builtin_amdgcn_mfma_f32_16x16x32_bf16(av0, aA[kf], ac0, 0, 0, 0);
      ac1 = __builtin_amdgcn_mfma_f32_16x16x32_bf16(av1, aA[kf], ac1, 0, 0, 0);
      ac0 = __builtin_amdgcn_mfma_f32_16x16x32_bf16(av0, aS[kf], ac0, 0, 0, 0);
      ac1 = __builtin_amdgcn_mfma_f32_16x16x32_bf16(av1, aS[kf], ac1, 0, 0, 0);
    }
    __builtin_amdgcn_s_setprio(0);
    float tm = fmaxf(fmaxf(fmaxf(ac0[0], ac0[1]), fmaxf(ac0[2], ac0[3])),
                     fmaxf(fmaxf(ac1[0], ac1[1]), fmaxf(ac1[2], ac1[3])));
    tm = fmaxf(tm, __shfl_xor(tm, 16));
    tm = fmaxf(tm, __shfl_xor(tm, 32));
    float mNew = fmaxf(mRun, tm);
    float scale = __expf(mRun - mNew);
    float p0 = __expf(ac0[0] - mNew), p1 = __expf(ac0[1] - mNew);
    float p2 = __expf(ac0[2] - mNew), p3 = __expf(ac0[3] - mNew);
    float q0 = __expf(ac1[0] - mNew), q1 = __expf(ac1[1] - mNew);
    float q2 = __expf(ac1[2] - mNew), q3 = __expf(ac1[3] - mNew);
    float cs = ((p0 + p1) + (p2 + p3)) + ((q0 + q1) + (q2 + q3));
    cs += __shfl_xor(cs, 16);
    cs += __shfl_xor(cs, 32);
    mRun = mNew;
    sRun = sRun * scale + cs;
    if (l < 16) corrL[lm][(w << 3) + step] = mRun;
    unsigned int d0 = (unsigned int)f2bf_rne(p0) |
                      (((unsigned int)f2bf_rne(p1)) << 16);
    unsigned int d1 = (unsigned int)f2bf_rne(p2) |
                      (((unsigned int)f2bf_rne(p3)) << 16);
    unsigned int e0 = (unsigned int)f2bf_rne(q0) |
                      (((unsigned int)f2bf_rne(q1)) << 16);
    unsigned int e1 = (unsigned int)f2bf_rne(q2) |
                      (((unsigned int)f2bf_rne(q3)) << 16);
    unsigned int A0 = (unsigned int)__shfl((int)d0, src1);
    unsigned int A1 = (unsigned int)__shfl((int)d1, src1);
    unsigned int B0 = (unsigned int)__shfl((int)d0, src2);
    unsigned int B1 = (unsigned int)__shfl((int)d1, src2);
    unsigned int C0 = (unsigned int)__shfl((int)e0, src1);
    unsigned int C1 = (unsigned int)__shfl((int)e1, src1);
    unsigned int D0 = (unsigned int)__shfl((int)e0, src2);
    unsigned int D1 = (unsigned int)__shfl((int)e1, src2);
    Pr[step][0] = hi2 ? C0 : A0;
    Pr[step][1] = hi2 ? C1 : A1;
    Pr[step][2] = hi2 ? D0 : B0;
    Pr[step][3] = hi2 ? D1 : B1;
  }
  if (l < 16) {
    statsL[w][lm][0] = mRun;
    statsL[w][lm][1] = sRun;
  }
  __syncthreads();

  if (t < 16) {
    float mF = -3.0e38f;
#pragma unroll
    for (int qq = 0; qq < 4; ++qq) mF = fmaxf(mF, statsL[qq][t][0]);
    float sF = 0.0f;
#pragma unroll
    for (int qq = 0; qq < 4; ++qq)
      sF += statsL[qq][t][1] * __expf(statsL[qq][t][0] - mF);
    mFinL[t] = mF;
    invL[t] = 1.0f / sF;
  }
  __syncthreads();

  {
    int e = t * 2;
#pragma unroll
    for (int i = 0; i < 2; ++i) {
      int row = (e + i) >> 5;
      int col = (e + i) & 31;
      corrL[row][col] = __expf(corrL[row][col] - mFinL[row]) * invL[row];
    }
  }
  __syncthreads();

#pragma unroll
  for (int s = 0; s < 8; ++s) {
    float corr = corrL[lm][(w << 3) + s];
#pragma unroll
    for (int j = 0; j < 4; ++j) {
      unsigned int u = Pr[s][j];
      float lo = __builtin_bit_cast(float, u << 16);
      float hi = __builtin_bit_cast(float, u & 0xffff0000u);
      Pr[s][j] = (unsigned int)f2bf_rne(lo * corr) |
                 (((unsigned int)f2bf_rne(hi * corr)) << 16);
    }
  }

  f32x4 oacc[13];
#pragma unroll
  for (int i = 0; i < 13; ++i) oacc[i] = (f32x4)0.f;

  __builtin_amdgcn_s_setprio(1);
#pragma unroll
  for (int s = 0; s < 8; ++s) {
    uint4v pu;
    pu.x = Pr[s][0]; pu.y = Pr[s][1]; pu.z = Pr[s][2]; pu.w = Pr[s][3];
    short8 pf = __builtin_bit_cast(short8, pu);
    const unsigned short* gbase =
        gP + ((size_t)(b * 208) << 10) + (w << 8) + (s << 5) + lg * 8;
#pragma unroll
    for (int ct = 0; ct < 13; ++ct) {
      int c = (ct << 4) + lm;
      short8 gv = *(const short8*)(gbase + ((size_t)c << 10));
      oacc[ct] = __builtin_amdgcn_mfma_f32_16x16x32_bf16(pf, gv, oacc[ct], 0, 0, 0);
    }
  }
  __builtin_amdgcn_s_setprio(0);

  for (int rnd = 0; rnd < 4; ++rnd) {
    if (w == rnd) {
#pragma unroll
      for (int ct = 0; ct < 13; ++ct) {
#pragma unroll
        for (int r = 0; r < 4; ++r) {
          int n = (lg << 2) + r;
          int c = (ct << 4) + lm;
          if (rnd == 0) outAcc[n][c] = oacc[ct][r];
          else outAcc[n][c] += oacc[ct][r];
        }
      }
    }
    __syncthreads();
  }

  {
    int lane16 = t & 15;
    int grp = t >> 4;
    for (int c = grp; c < 200; c += 16)
      out[(((size_t)(b * 200 + c)) << 12) + n0 + lane16] = outAcc[lane16][c];
  }
}

// ---------------------------------------------------------------------------
extern "C" void kernel_launch(void* const* d_in, const int* in_sizes, int n_in,
                              void* d_out, int out_size, void* d_ws,
                              size_t ws_size, hipStream_t stream) {
  const float* x  = (const float*)d_in[0];
  const float* tw = (const float*)d_in[1];
  const float* tb = (const float*)d_in[2];
  const float* pw = (const float*)d_in[3];
  const float* pb = (const float*)d_in[4];
  const float* gw = (const float*)d_in[5];
  const float* gb = (const float*)d_in[6];
  float* out = (float*)d_out;

  unsigned short* ws_us = (unsigned short*)d_ws;
  unsigned short* thd   = ws_us;               //  8,388,608 us
  unsigned short* phd   = ws_us + 8388608;     //  2,097,152
  unsigned short* gP    = ws_us + 10485760;    //  1,703,936
  unsigned short* xTi   = ws_us + 12189696;    //  5,017,600
  unsigned short* wTi   = ws_us + 17207296;    //  2,809,856
  unsigned short* xTi_h = ws_us + 20017152;    //  2,508,800
  unsigned short* wTi_s = ws_us + 22525952;    //    602,112
  float* biasPad = (float*)(ws_us + 23128064); //  448 f  (~46.3 MB total)

  prep_x<<<560, 256, 0, stream>>>(x, (unsigned int*)xTi, (unsigned int*)xTi_h);
  prep_w<<<6664, 256, 0, stream>>>(tw, pw, gw, tb, pb, gb,
                                   (unsigned int*)wTi, (unsigned int*)wTi_s,
                                   biasPad);

  convmfma_kernel<<<dim3(64, 7), 256, 0, stream>>>(
      xTi, wTi, xTi_h, wTi_s, biasPad, (unsigned int*)thd,
      (unsigned int*)phd, gP);
  attn_kernel<<<2048, 256, 0, stream>>>(thd, phd, gP, out);
}

// Round 20
// 408.361 us; speedup vs baseline: 1.2280x; 1.0142x over previous
//
#include <hip/hip_runtime.h>
#include <cstdint>
#include <cstddef>

#define BATCH 8
#define CIN 64
#define HIN 70
#define HOUT 64
#define NPIX 4096
#define MPIX 1024

typedef __attribute__((ext_vector_type(8))) short short8;
typedef __attribute__((ext_vector_type(4))) float f32x4;
typedef __attribute__((ext_vector_type(4))) unsigned int uint4v;

__device__ __forceinline__ unsigned short f2bf_rne(float f) {
  unsigned int u = __builtin_bit_cast(unsigned int, f);
  unsigned int r = (u + 0x7FFFu + ((u >> 16) & 1u)) >> 16;
  return (unsigned short)r;
}

__device__ __forceinline__ unsigned int rot16(unsigned int u) {
  return (u >> 16) | (u << 16);
}

__device__ __forceinline__ short8 rot16x4(short8 v) {
  uint4v u = __builtin_bit_cast(uint4v, v);
  u.x = rot16(u.x); u.y = rot16(u.y); u.z = rot16(u.z); u.w = rot16(u.w);
  return __builtin_bit_cast(short8, u);
}

// ---------------------------------------------------------------------------
// prep_all: blocks 0..559 = prep_x (x -> xTi dual + xTi_h hi-only);
//           blocks 560+   = prep_w (weights -> wTi dual + wTi_s + biasPad)
// ---------------------------------------------------------------------------
__global__ __launch_bounds__(256) void prep_all(
    const float* __restrict__ x,
    const float* __restrict__ tw, const float* __restrict__ pw,
    const float* __restrict__ gw,
    const float* __restrict__ tb, const float* __restrict__ pb,
    const float* __restrict__ gb,
    unsigned int* __restrict__ xTi, unsigned int* __restrict__ xTi_h,
    unsigned int* __restrict__ wTi, unsigned int* __restrict__ wTi_s,
    float* __restrict__ biasPad) {
  const int t = threadIdx.x;
  if (blockIdx.x < 560) {
    __shared__ float tile[64][71];
    const int blk = blockIdx.x;
    const int b = blk / 70;
    const int r = blk - b * 70;
    for (int i = t; i < 64 * 70; i += 256) {
      int ci = i / 70;
      int c = i - ci * 70;
      tile[ci][c] = x[(((size_t)(b * 64 + ci)) * 70 + r) * 70 + c];
    }
    __syncthreads();
    for (int i = t; i < 70 * 64; i += 256) {
      int c = i >> 6;
      int ci = i & 63;
      float a = tile[ci][c];
      unsigned short hi = f2bf_rne(a);
      float hif = __builtin_bit_cast(float, ((unsigned int)hi) << 16);
      unsigned short lo = f2bf_rne(a - hif);
      xTi[(((size_t)(b * 70 + r)) * 70 + c) * 64 + ci] =
          (unsigned int)hi | (((unsigned int)lo) << 16);
    }
    for (int i = t; i < 70 * 32; i += 256) {
      int c = i >> 5;
      int dwi = i & 31;
      unsigned int h0 = f2bf_rne(tile[2 * dwi][c]);
      unsigned int h1 = f2bf_rne(tile[2 * dwi + 1][c]);
      xTi_h[(((size_t)(b * 70 + r)) * 70 + c) * 32 + dwi] = h0 | (h1 << 16);
    }
    return;
  }
  int gid = (blockIdx.x - 560) * 256 + t;
  if (gid < 1404928) {  // 49*448*64 dual dwords
    if (gid < 448) {
      float bv = 0.0f;
      if (gid < 100) bv = tb[gid];
      else if (gid < 200) bv = pb[gid - 100];
      else if (gid < 400) bv = gb[gid - 200];
      biasPad[gid] = bv;
    }
    int ci = gid & 63;
    int OC = (gid >> 6) % 448;
    int s = gid / (448 * 64);
    float v = 0.0f;
    if (OC < 100) v = tw[((size_t)(OC * 64 + ci)) * 49 + s];
    else if (OC < 200) v = pw[((size_t)((OC - 100) * 64 + ci)) * 49 + s];
    else if (OC < 400) v = gw[((size_t)((OC - 200) * 64 + ci)) * 49 + s];
    unsigned short hi = f2bf_rne(v);
    float hif = __builtin_bit_cast(float, ((unsigned int)hi) << 16);
    unsigned short lo = f2bf_rne(v - hif);
    wTi[gid] = (unsigned int)hi | (((unsigned int)lo) << 16);
  } else if (gid < 1404928 + 301056) {  // 49*192*32 single dwords
    int g2 = gid - 1404928;
    int dwi = g2 & 31;
    int OCl = (g2 >> 5) % 192;
    int s = g2 / (192 * 32);
    int gc = 56 + OCl;
    float v0 = 0.0f, v1 = 0.0f;
    if (gc < 200) {
      v0 = gw[((size_t)(gc * 64 + 2 * dwi)) * 49 + s];
      v1 = gw[((size_t)(gc * 64 + 2 * dwi + 1)) * 49 + s];
    }
    wTi_s[g2] = (unsigned int)f2bf_rne(v0) |
                (((unsigned int)f2bf_rne(v1)) << 16);
  }
}

// ---------------------------------------------------------------------------
// conv_body (r13-verified logic; smem hoisted to wrapper).
// DUAL: theta/phi/g[0..55] dual-bf16.  !DUAL: g[56..199] single-bf16.
// ---------------------------------------------------------------------------
template <bool DUAL>
__device__ __forceinline__ void conv_body(
    char* smem, int ocy,
    const unsigned short* __restrict__ xT,
    const unsigned short* __restrict__ wT,
    const float* __restrict__ biasPad,
    unsigned int* __restrict__ thd_dw,
    unsigned int* __restrict__ phd_dw,
    unsigned short* __restrict__ gP) {
  const int LDSW = 62720;
  const int NCH = DUAL ? 4 : 2;
  const int XS = DUAL ? 128 : 64;
  const int WOCS = DUAL ? 128 : 64;
  const int WSTRIDE = DUAL ? 57344 : 12288;

  const int gx = blockIdx.x;
  const int b = gx >> 3;
  const int ptile = gx & 7;
  const int oy0 = ptile * 8;
  const int oc0 = (DUAL ? 0 : 256) + (ocy << 6);
  const int oc0W = DUAL ? oc0 : (ocy << 6);

  const int t = threadIdx.x;
  const int wv = t >> 6;
  const int l = t & 63;
  const int lm = l & 15;
  const int lg = l >> 4;

  int wdstOff_[2];
  const unsigned short* wsrc_[2];
  const int keyA = ((lm >> 1) & 3) << 4;
  const int laneA = (lm << 6) + ((lg << 4) ^ keyA);

  f32x4 acc[4][2][4];
#pragma unroll
  for (int j = 0; j < 4; ++j)
#pragma unroll
    for (int rr = 0; rr < 2; ++rr)
#pragma unroll
      for (int f = 0; f < 4; ++f) acc[j][rr][f] = (f32x4)0.0f;

  for (int chunk = 0; chunk < NCH; ++chunk) {
    for (int i = t; i < 3920; i += 256) {
      int idx70 = i >> 2;
      int s16 = i & 3;
      int rr = idx70 / 70;
      int cc = idx70 - rr * 70;
      const unsigned short* src =
          xT + ((size_t)((b * 70 + oy0 + rr) * 70 + cc)) * XS +
          (chunk << 5) + (s16 << 3);
      short8 v = *(const short8*)src;
      int dst = (idx70 << 6) + ((s16 << 4) ^ (((cc >> 1) & 3) << 4));
      *(short8*)(smem + dst) = v;
    }
    short8 wreg[2];
#pragma unroll
    for (int u2 = 0; u2 < 2; ++u2) {
      int u = t + (u2 << 8);
      int sub = u >> 8;
      int oc_t = (u >> 2) & 63;
      int q = u & 3;
      wdstOff_[u2] =
          sub * 4096 + (oc_t << 6) + ((q << 4) ^ (((oc_t >> 1) & 3) << 4));
      wsrc_[u2] = wT + (size_t)(oc0W + oc_t) * WOCS + (chunk << 5) + (q << 3);
      wreg[u2] = *(const short8*)(wsrc_[u2] + (size_t)sub * WSTRIDE);
      *(short8*)(smem + LDSW + wdstOff_[u2]) = wreg[u2];
      wreg[u2] = *(const short8*)(wsrc_[u2] + (size_t)(2 + sub) * WSTRIDE);
    }
    __syncthreads();

    for (int p = 0; p < 25; ++p) {
      const char* slotBase = smem + LDSW + ((p & 1) << 13);
#pragma unroll
      for (int halfs = 0; halfs < 2; ++halfs) {
        const int s = 2 * p + halfs;
        if (s <= 48) {
          const int ky = s / 7;
          const int kx = s - ky * 7;
          const char* wb = slotBase + (halfs << 12) + laneA;
          short8 aW[4], aS[4];
#pragma unroll
          for (int j = 0; j < 4; ++j) {
            aW[j] = *(const short8*)(wb + j * 1024);
            if (DUAL) aS[j] = rot16x4(aW[j]);
          }
          const int klx = kx + lm;
          const int key = ((klx >> 1) & 3) << 4;
#pragma unroll
          for (int rr = 0; rr < 2; ++rr) {
            const char* bbase =
                smem + ((2 * wv + rr + ky) * 70 + klx) * 64 + ((lg << 4) ^ key);
#pragma unroll
            for (int f = 0; f < 4; ++f) {
              short8 bf = *(const short8*)(bbase + f * 1024);
#pragma unroll
              for (int j = 0; j < 4; ++j) {
                acc[j][rr][f] = __builtin_amdgcn_mfma_f32_16x16x32_bf16(
                    aW[j], bf, acc[j][rr][f], 0, 0, 0);
                if (DUAL)
                  acc[j][rr][f] = __builtin_amdgcn_mfma_f32_16x16x32_bf16(
                      aS[j], bf, acc[j][rr][f], 0, 0, 0);
              }
            }
          }
        }
      }
      if (p < 24) {
#pragma unroll
        for (int u2 = 0; u2 < 2; ++u2) {
          *(short8*)(smem + LDSW + (((p + 1) & 1) << 13) + wdstOff_[u2]) =
              wreg[u2];
          if (p < 23) {
            int sub = (t + (u2 << 8)) >> 8;
            int snext = 2 * (p + 2) + sub;
            if (snext > 48) snext = 48;
            wreg[u2] = *(const short8*)(wsrc_[u2] + (size_t)snext * WSTRIDE);
          }
        }
      }
      __syncthreads();
    }
  }

  float bia[4][4];
#pragma unroll
  for (int j = 0; j < 4; ++j)
#pragma unroll
    for (int r = 0; r < 4; ++r) bia[j][r] = biasPad[oc0 + j * 16 + lg * 4 + r];

  if (DUAL) {
#pragma unroll
    for (int j = 0; j < 4; ++j) {
#pragma unroll
      for (int rr = 0; rr < 2; ++rr) {
#pragma unroll
        for (int f = 0; f < 4; ++f) {
#pragma unroll
          for (int r = 0; r < 4; ++r) {
            int ch = oc0 + j * 16 + lg * 4 + r;
            if (ch < 128) {
              int n = (oy0 + 2 * wv + rr) * 64 + f * 16 + lm;
              unsigned int outw = 0u;
              if (ch < 100) {
                float v = acc[j][rr][f][r] + bia[j][r];
                unsigned short hi = f2bf_rne(v);
                float hif =
                    __builtin_bit_cast(float, ((unsigned int)hi) << 16);
                unsigned short lo = f2bf_rne(v - hif);
                outw = (unsigned int)hi | (((unsigned int)lo) << 16);
              }
              thd_dw[(((size_t)(b << 12) + n) << 7) + ch] = outw;
            }
          }
        }
      }
    }
  }

#pragma unroll
  for (int j = 0; j < 4; ++j) {
#pragma unroll
    for (int f = 0; f < 4; ++f) {
#pragma unroll
      for (int r = 0; r < 4; ++r) {
        float v0 = acc[j][0][f][r] + bia[j][r];
        float v1 = acc[j][1][f][r] + bia[j][r];
        float vr = fmaxf(v0, v1);
        float vn = fmaxf(vr, __shfl_xor(vr, 1));
        if (!(lm & 1)) {
          int ch = oc0 + j * 16 + lg * 4 + r;
          int m = (((oy0 >> 1) + wv) << 5) + f * 8 + (lm >> 1);
          if (DUAL) {
            if (ch >= 100 && ch < 200) {
              int c = ch - 100;
              unsigned short hi = f2bf_rne(vn);
              float hif = __builtin_bit_cast(float, ((unsigned int)hi) << 16);
              unsigned short lo = f2bf_rne(vn - hif);
              phd_dw[(((size_t)(b << 10) + m) << 7) + c] =
                  (unsigned int)hi | (((unsigned int)lo) << 16);
            } else if (ch >= 200) {
              gP[((size_t)(b * 208 + (ch - 200)) << 10) + m] = f2bf_rne(vn);
              if (ch < 228)
                phd_dw[(((size_t)(b << 10) + m) << 7) + (ch - 100)] = 0u;
            }
          } else {
            int cg = ch - 200;
            if (cg < 208)
              gP[((size_t)(b * 208 + cg) << 10) + m] = f2bf_rne(vn);
          }
        }
      }
    }
  }
}

// ---------------------------------------------------------------------------
// convmfma merged (r19-verified): grid (64,7); y<4 DUAL else SINGLE.
// ---------------------------------------------------------------------------
__global__ __launch_bounds__(256, 2) void convmfma_kernel(
    const unsigned short* __restrict__ xTi,
    const unsigned short* __restrict__ wTi,
    const unsigned short* __restrict__ xTi_h,
    const unsigned short* __restrict__ wTi_s,
    const float* __restrict__ biasPad,
    unsigned int* __restrict__ thd_dw,
    unsigned int* __restrict__ phd_dw,
    unsigned short* __restrict__ gP) {
  __shared__ __align__(16) char smem[62720 + 16384];
  if (blockIdx.y < 4)
    conv_body<true>(smem, blockIdx.y, xTi, wTi, biasPad, thd_dw, phd_dw, gP);
  else
    conv_body<false>(smem, blockIdx.y - 4, xTi_h, wTi_s, biasPad, thd_dw,
                     phd_dw, gP);
}

// ---------------------------------------------------------------------------
// attn (r18 structure + 4-chain QK^T): batch->XCD swizzle, setprio, and the
// QK^T accumulators split kf 0-3 / 4-7 into independent chains (ac*,ac*b)
// to halve the MFMA dependency-chain stall. +8 VGPR (target <128).
// ---------------------------------------------------------------------------
__global__ __launch_bounds__(256) void attn_kernel(
    const unsigned short* __restrict__ thd,  // [8][4096][256]
    const unsigned short* __restrict__ phd,  // [8][1024][256]
    const unsigned short* __restrict__ gP,   // [8][208][1024]
    float* __restrict__ out) {               // [8][200][4096]
  __shared__ __align__(16) float outAcc[16][212];
  __shared__ float corrL[16][33];
  __shared__ float statsL[4][16][2];
  __shared__ float mFinL[16];
  __shared__ float invL[16];

  const int bid = blockIdx.x;  // 0..2047
  const int b = bid & 7;
  const int n0 = (bid >> 3) << 4;
  const int t = threadIdx.x;
  const int w = t >> 6;
  const int l = t & 63;
  const int lm = l & 15;
  const int lg = l >> 4;

  short8 aA[8], aS[8];
  {
    const unsigned short* ap =
        thd + (((size_t)(b << 12) + n0 + lm) << 8) + lg * 8;
#pragma unroll
    for (int kf = 0; kf < 8; ++kf) {
      short8 v = *(const short8*)(ap + kf * 32);
      aA[kf] = v;
      aS[kf] = rot16x4(v);
    }
  }

  float mRun = -3.0e38f, sRun = 0.0f;
  unsigned int Pr[8][4];

  const int src1 = ((lg & 1) << 5) + lm;
  const int src2 = src1 + 16;
  const bool hi2 = (lg >> 1) != 0;

#pragma unroll
  for (int step = 0; step < 8; ++step) {
    const int m0 = (w << 8) + (step << 5);
    f32x4 ac0 = (f32x4)0.f, ac1 = (f32x4)0.f;
    f32x4 ac0b = (f32x4)0.f, ac1b = (f32x4)0.f;
    const unsigned short* bp0 =
        phd + (((size_t)(b << 10) + m0 + lm) << 8) + lg * 8;
    const unsigned short* bp1 = bp0 + (16 << 8);
    __builtin_amdgcn_s_setprio(1);
#pragma unroll
    for (int kf = 0; kf < 4; ++kf) {
      short8 av0 = *(const short8*)(bp0 + kf * 32);
      short8 av1 = *(const short8*)(bp1 + kf * 32);
      short8 av0b = *(const short8*)(bp0 + (kf + 4) * 32);
      short8 av1b = *(const short8*)(bp1 + (kf + 4) * 32);
      ac0 = __builtin_amdgcn_mfma_f32_16x16x32_bf16(av0, aA[kf], ac0, 0, 0, 0);
      ac1 = __builtin_amdgcn_mfma_f32_16x16x32_bf16(av1, aA[kf], ac1, 0, 0, 0);
      ac0b = __builtin_amdgcn_mfma_f32_16x16x32_bf16(av0b, aA[kf + 4], ac0b, 0, 0, 0);
      ac1b = __builtin_amdgcn_mfma_f32_16x16x32_bf16(av1b, aA[kf + 4], ac1b, 0, 0, 0);
      ac0 = __builtin_amdgcn_mfma_f32_16x16x32_bf16(av0, aS[kf], ac0, 0, 0, 0);
      ac1 = __builtin_amdgcn_mfma_f32_16x16x32_bf16(av1, aS[kf], ac1, 0, 0, 0);
      ac0b = __builtin_amdgcn_mfma_f32_16x16x32_bf16(av0b, aS[kf + 4], ac0b, 0, 0, 0);
      ac1b = __builtin_amdgcn_mfma_f32_16x16x32_bf16(av1b, aS[kf + 4], ac1b, 0, 0, 0);
    }
    __builtin_amdgcn_s_setprio(0);
    ac0 += ac0b;
    ac1 += ac1b;
    float tm = fmaxf(fmaxf(fmaxf(ac0[0], ac0[1]), fmaxf(ac0[2], ac0[3])),
                     fmaxf(fmaxf(ac1[0], ac1[1]), fmaxf(ac1[2], ac1[3])));
    tm = fmaxf(tm, __shfl_xor(tm, 16));
    tm = fmaxf(tm, __shfl_xor(tm, 32));
    float mNew = fmaxf(mRun, tm);
    float scale = __expf(mRun - mNew);
    float p0 = __expf(ac0[0] - mNew), p1 = __expf(ac0[1] - mNew);
    float p2 = __expf(ac0[2] - mNew), p3 = __expf(ac0[3] - mNew);
    float q0 = __expf(ac1[0] - mNew), q1 = __expf(ac1[1] - mNew);
    float q2 = __expf(ac1[2] - mNew), q3 = __expf(ac1[3] - mNew);
    float cs = ((p0 + p1) + (p2 + p3)) + ((q0 + q1) + (q2 + q3));
    cs += __shfl_xor(cs, 16);
    cs += __shfl_xor(cs, 32);
    mRun = mNew;
    sRun = sRun * scale + cs;
    if (l < 16) corrL[lm][(w << 3) + step] = mRun;
    unsigned int d0 = (unsigned int)f2bf_rne(p0) |
                      (((unsigned int)f2bf_rne(p1)) << 16);
    unsigned int d1 = (unsigned int)f2bf_rne(p2) |
                      (((unsigned int)f2bf_rne(p3)) << 16);
    unsigned int e0 = (unsigned int)f2bf_rne(q0) |
                      (((unsigned int)f2bf_rne(q1)) << 16);
    unsigned int e1 = (unsigned int)f2bf_rne(q2) |
                      (((unsigned int)f2bf_rne(q3)) << 16);
    unsigned int A0 = (unsigned int)__shfl((int)d0, src1);
    unsigned int A1 = (unsigned int)__shfl((int)d1, src1);
    unsigned int B0 = (unsigned int)__shfl((int)d0, src2);
    unsigned int B1 = (unsigned int)__shfl((int)d1, src2);
    unsigned int C0 = (unsigned int)__shfl((int)e0, src1);
    unsigned int C1 = (unsigned int)__shfl((int)e1, src1);
    unsigned int D0 = (unsigned int)__shfl((int)e0, src2);
    unsigned int D1 = (unsigned int)__shfl((int)e1, src2);
    Pr[step][0] = hi2 ? C0 : A0;
    Pr[step][1] = hi2 ? C1 : A1;
    Pr[step][2] = hi2 ? D0 : B0;
    Pr[step][3] = hi2 ? D1 : B1;
  }
  if (l < 16) {
    statsL[w][lm][0] = mRun;
    statsL[w][lm][1] = sRun;
  }
  __syncthreads();

  if (t < 16) {
    float mF = -3.0e38f;
#pragma unroll
    for (int qq = 0; qq < 4; ++qq) mF = fmaxf(mF, statsL[qq][t][0]);
    float sF = 0.0f;
#pragma unroll
    for (int qq = 0; qq < 4; ++qq)
      sF += statsL[qq][t][1] * __expf(statsL[qq][t][0] - mF);
    mFinL[t] = mF;
    invL[t] = 1.0f / sF;
  }
  __syncthreads();

  {
    int e = t * 2;
#pragma unroll
    for (int i = 0; i < 2; ++i) {
      int row = (e + i) >> 5;
      int col = (e + i) & 31;
      corrL[row][col] = __expf(corrL[row][col] - mFinL[row]) * invL[row];
    }
  }
  __syncthreads();

#pragma unroll
  for (int s = 0; s < 8; ++s) {
    float corr = corrL[lm][(w << 3) + s];
#pragma unroll
    for (int j = 0; j < 4; ++j) {
      unsigned int u = Pr[s][j];
      float lo = __builtin_bit_cast(float, u << 16);
      float hi = __builtin_bit_cast(float, u & 0xffff0000u);
      Pr[s][j] = (unsigned int)f2bf_rne(lo * corr) |
                 (((unsigned int)f2bf_rne(hi * corr)) << 16);
    }
  }

  f32x4 oacc[13];
#pragma unroll
  for (int i = 0; i < 13; ++i) oacc[i] = (f32x4)0.f;

  __builtin_amdgcn_s_setprio(1);
#pragma unroll
  for (int s = 0; s < 8; ++s) {
    uint4v pu;
    pu.x = Pr[s][0]; pu.y = Pr[s][1]; pu.z = Pr[s][2]; pu.w = Pr[s][3];
    short8 pf = __builtin_bit_cast(short8, pu);
    const unsigned short* gbase =
        gP + ((size_t)(b * 208) << 10) + (w << 8) + (s << 5) + lg * 8;
#pragma unroll
    for (int ct = 0; ct < 13; ++ct) {
      int c = (ct << 4) + lm;
      short8 gv = *(const short8*)(gbase + ((size_t)c << 10));
      oacc[ct] = __builtin_amdgcn_mfma_f32_16x16x32_bf16(pf, gv, oacc[ct], 0, 0, 0);
    }
  }
  __builtin_amdgcn_s_setprio(0);

  for (int rnd = 0; rnd < 4; ++rnd) {
    if (w == rnd) {
#pragma unroll
      for (int ct = 0; ct < 13; ++ct) {
#pragma unroll
        for (int r = 0; r < 4; ++r) {
          int n = (lg << 2) + r;
          int c = (ct << 4) + lm;
          if (rnd == 0) outAcc[n][c] = oacc[ct][r];
          else outAcc[n][c] += oacc[ct][r];
        }
      }
    }
    __syncthreads();
  }

  {
    int lane16 = t & 15;
    int grp = t >> 4;
    for (int c = grp; c < 200; c += 16)
      out[(((size_t)(b * 200 + c)) << 12) + n0 + lane16] = outAcc[lane16][c];
  }
}

// ---------------------------------------------------------------------------
extern "C" void kernel_launch(void* const* d_in, const int* in_sizes, int n_in,
                              void* d_out, int out_size, void* d_ws,
                              size_t ws_size, hipStream_t stream) {
  const float* x  = (const float*)d_in[0];
  const float* tw = (const float*)d_in[1];
  const float* tb = (const float*)d_in[2];
  const float* pw = (const float*)d_in[3];
  const float* pb = (const float*)d_in[4];
  const float* gw = (const float*)d_in[5];
  const float* gb = (const float*)d_in[6];
  float* out = (float*)d_out;

  unsigned short* ws_us = (unsigned short*)d_ws;
  unsigned short* thd   = ws_us;               //  8,388,608 us
  unsigned short* phd   = ws_us + 8388608;     //  2,097,152
  unsigned short* gP    = ws_us + 10485760;    //  1,703,936
  unsigned short* xTi   = ws_us + 12189696;    //  5,017,600
  unsigned short* wTi   = ws_us + 17207296;    //  2,809,856
  unsigned short* xTi_h = ws_us + 20017152;    //  2,508,800
  unsigned short* wTi_s = ws_us + 22525952;    //    602,112
  float* biasPad = (float*)(ws_us + 23128064); //  448 f  (~46.3 MB total)

  prep_all<<<560 + 6664, 256, 0, stream>>>(
      x, tw, pw, gw, tb, pb, gb, (unsigned int*)xTi, (unsigned int*)xTi_h,
      (unsigned int*)wTi, (unsigned int*)wTi_s, biasPad);

  convmfma_kernel<<<dim3(64, 7), 256, 0, stream>>>(
      xTi, wTi, xTi_h, wTi_s, biasPad, (unsigned int*)thd,
      (unsigned int*)phd, gP);
  attn_kernel<<<2048, 256, 0, stream>>>(thd, phd, gP, out);
}